// Round 3
// baseline (162.178 us; speedup 1.0000x reference)
//
#include <hip/hip_runtime.h>
#include <hip/hip_bf16.h>

typedef __attribute__((ext_vector_type(8))) short short8;
typedef __attribute__((ext_vector_type(4))) short short4v;
typedef __attribute__((ext_vector_type(4))) float f32x4;
typedef __attribute__((ext_vector_type(16))) float f32x16;
typedef __attribute__((ext_vector_type(4))) unsigned int u32x4;

#define S_LEN 2048
#define D_DIM 128
#define BM 128      // q rows per block = 4 waves x 32
#define BN 64       // kv rows per tile
#define KST 136     // K lds row stride (shorts): 272B, 16B-aligned rows
#define OST 132     // O-transpose lds row stride (floats)
#define VSWZ(d) ((((d) >> 2) & 7) << 4)   // byte XOR swizzle for V lds

__device__ __forceinline__ unsigned short bfbits(float f) {
  return __builtin_bit_cast(unsigned short, __float2bfloat16(f));
}
__device__ __forceinline__ unsigned int pk2(float lo, float hi) {
  return (unsigned int)bfbits(lo) | ((unsigned int)bfbits(hi) << 16);
}
__device__ __forceinline__ void swap32(unsigned int &a, unsigned int &b) {
  // a' = [a_lo | b_lo], b' = [a_hi | b_hi]  (halves = lanes <32 / >=32)
  asm volatile("v_permlane32_swap_b32 %0, %1" : "+v"(a), "+v"(b));
}
__device__ __forceinline__ f32x16 zero16() {
  f32x16 z;
  #pragma unroll
  for (int i = 0; i < 16; ++i) z[i] = 0.f;
  return z;
}

extern "C" __global__ void __launch_bounds__(256, 2)
fa_fwd_kernel(const float* __restrict__ Qg, const float* __restrict__ Kg,
              const float* __restrict__ Vg, float* __restrict__ Og)
{
  __shared__ __align__(16) char smem[67584];
  short* Ksh = (short*)smem;                 // [2][64*KST] bf16, 34816 B
  char*  Vsh = smem + 2 * 64 * KST * 2;      // [2][128 rows x 128 B] swizzled Vt, 32768 B
  float* Osh = (float*)smem;                 // [128][OST] f32, epilogue reuse (67584 B)

  const int bh = blockIdx.x;
  const int qt = 15 - (int)blockIdx.y;       // heavy q-tiles dispatch first
  const int m0 = qt * BM;
  const int tid = threadIdx.x;
  const int wv  = tid >> 6;
  const int ln  = tid & 63;
  const int l31 = ln & 31;
  const int hi  = ln >> 5;

  const size_t base = (size_t)bh * S_LEN * D_DIM;
  const float* Qb = Qg + base;
  const float* Kb = Kg + base;
  const float* Vb = Vg + base;
  float*       Ob = Og + base;

  const float scale = 0.08838834764831845f;  // 1/sqrt(128)
  const int wrow_lo = m0 + wv * 32;          // wave's first q row
  const int vg = tid & 31, vp = tid >> 5;    // V staging coords

  // ---- Q^T B-frags: lane holds q = l31, k-slice = hi*8.. per 16-d chunk ----
  short8 qf[8];
  {
    const float* qsrc = Qb + (size_t)(wrow_lo + l31) * D_DIM + hi * 8;
    #pragma unroll
    for (int dc = 0; dc < 8; ++dc) {
      f32x4 a = *(const f32x4*)(qsrc + dc * 16);
      f32x4 b = *(const f32x4*)(qsrc + dc * 16 + 4);
      short8 f;
      f[0] = (short)bfbits(a[0] * scale); f[1] = (short)bfbits(a[1] * scale);
      f[2] = (short)bfbits(a[2] * scale); f[3] = (short)bfbits(a[3] * scale);
      f[4] = (short)bfbits(b[0] * scale); f[5] = (short)bfbits(b[1] * scale);
      f[6] = (short)bfbits(b[2] * scale); f[7] = (short)bfbits(b[3] * scale);
      qf[dc] = f;
    }
  }

  f32x16 oacc[4];
  #pragma unroll
  for (int i = 0; i < 4; ++i) oacc[i] = zero16();
  float m_run = -INFINITY, l_run = 0.f;

  const int ntiles = 2 * qt + 2;

  // ---- prologue: stage tile 0 into buf 0 ----
  {
    #pragma unroll
    for (int i = 0; i < 8; ++i) {
      int idx = i * 256 + tid;
      f32x4 k4 = *(const f32x4*)(Kb + (size_t)(idx >> 5) * D_DIM + (idx & 31) * 4);
      short4v ks;
      ks[0] = (short)bfbits(k4[0]); ks[1] = (short)bfbits(k4[1]);
      ks[2] = (short)bfbits(k4[2]); ks[3] = (short)bfbits(k4[3]);
      *(short4v*)&Ksh[(idx >> 5) * KST + (idx & 31) * 4] = ks;
    }
    #pragma unroll
    for (int i = 0; i < 4; ++i) {
      int p = vp + i * 8;
      f32x4 r0 = *(const f32x4*)(Vb + (size_t)(2 * p) * D_DIM + vg * 4);
      f32x4 r1 = *(const f32x4*)(Vb + (size_t)(2 * p + 1) * D_DIM + vg * 4);
      #pragma unroll
      for (int j = 0; j < 4; ++j) {
        int d = vg * 4 + j;
        *(unsigned int*)(Vsh + ((d * 128 + p * 4) ^ VSWZ(d))) = pk2(r0[j], r1[j]);
      }
    }
  }
  __syncthreads();

  int cur = 0;
  for (int t = 0; t < ntiles; ++t) {
    const int kv0 = t * BN;
    const bool pf = (t + 1 < ntiles);
    const bool comp = (kv0 <= wrow_lo + 31);   // wave-uniform causal skip

    // ---- prefetch K(t+1) into regs (latency hides under QK^T) ----
    f32x4 kr[8];
    if (pf) {
      const float* Kt = Kb + (size_t)(t + 1) * BN * D_DIM;
      #pragma unroll
      for (int i = 0; i < 8; ++i) {
        int idx = i * 256 + tid;
        kr[i] = *(const f32x4*)(Kt + (size_t)(idx >> 5) * D_DIM + (idx & 31) * 4);
      }
    }

    f32x16 sacc[2];
    short8 pfrag[4];
    if (comp) {
      // ---- S^T = K (Q*scale)^T : lane gets col q=l31, rows = kv ----
      const short* Kl = Ksh + cur * 64 * KST;
      #pragma unroll
      for (int g = 0; g < 2; ++g) {
        sacc[g] = zero16();
        #pragma unroll
        for (int dc = 0; dc < 8; ++dc) {
          short8 kf = *(const short8*)&Kl[(g * 32 + l31) * KST + dc * 16 + hi * 8];
          sacc[g] = __builtin_amdgcn_mfma_f32_32x32x16_bf16(kf, qf[dc], sacc[g], 0, 0, 0);
        }
      }
    }

    // ---- write K(t+1) to other buffer ----
    if (pf) {
      short* Kd = Ksh + (cur ^ 1) * 64 * KST;
      #pragma unroll
      for (int i = 0; i < 8; ++i) {
        int idx = i * 256 + tid;
        short4v ks;
        ks[0] = (short)bfbits(kr[i][0]); ks[1] = (short)bfbits(kr[i][1]);
        ks[2] = (short)bfbits(kr[i][2]); ks[3] = (short)bfbits(kr[i][3]);
        *(short4v*)&Kd[(idx >> 5) * KST + (idx & 31) * 4] = ks;
      }
    }

    // ---- prefetch V(t+1) into regs (latency hides under softmax+PV) ----
    f32x4 vr0[4], vr1[4];
    if (pf) {
      const float* Vt = Vb + (size_t)(t + 1) * BN * D_DIM;
      #pragma unroll
      for (int i = 0; i < 4; ++i) {
        int p = vp + i * 8;
        vr0[i] = *(const f32x4*)(Vt + (size_t)(2 * p) * D_DIM + vg * 4);
        vr1[i] = *(const f32x4*)(Vt + (size_t)(2 * p + 1) * D_DIM + vg * 4);
      }
    }

    if (comp) {
      // ---- causal mask (one diagonal tile per wave) ----
      if (kv0 + BN - 1 > wrow_lo) {
        const int qg = wrow_lo + l31;
        #pragma unroll
        for (int g = 0; g < 2; ++g)
          #pragma unroll
          for (int r = 0; r < 16; ++r) {
            int kvg = kv0 + g * 32 + (r & 3) + 8 * (r >> 2) + 4 * hi;
            if (kvg > qg) sacc[g][r] = -INFINITY;
          }
      }

      // ---- online softmax, fully in-register (row = own q = l31) ----
      float tt[16];
      #pragma unroll
      for (int r = 0; r < 16; ++r) tt[r] = fmaxf(sacc[0][r], sacc[1][r]);
      #pragma unroll
      for (int s = 8; s > 0; s >>= 1)
        #pragma unroll
        for (int r = 0; r < s; ++r) tt[r] = fmaxf(tt[r], tt[r + s]);
      float m_t = fmaxf(tt[0], __shfl_xor(tt[0], 32));
      float m_new = fmaxf(m_run, m_t);
      float alpha = __expf(m_run - m_new);
      m_run = m_new;

      #pragma unroll
      for (int g = 0; g < 2; ++g)
        #pragma unroll
        for (int r = 0; r < 16; ++r)
          sacc[g][r] = __expf(sacc[g][r] - m_new);

      #pragma unroll
      for (int r = 0; r < 16; ++r) tt[r] = sacc[0][r] + sacc[1][r];
      #pragma unroll
      for (int s = 8; s > 0; s >>= 1)
        #pragma unroll
        for (int r = 0; r < s; ++r) tt[r] += tt[r + s];
      float rs = tt[0] + __shfl_xor(tt[0], 32);
      l_run = l_run * alpha + rs;

      #pragma unroll
      for (int dc = 0; dc < 4; ++dc)
        #pragma unroll
        for (int r = 0; r < 16; ++r) oacc[dc][r] *= alpha;

      // ---- P -> bf16 PV-fragments via pack + permlane32_swap (no LDS) ----
      #pragma unroll
      for (int g = 0; g < 2; ++g)
        #pragma unroll
        for (int c = 0; c < 2; ++c) {
          unsigned int A0 = pk2(sacc[g][c * 8 + 0], sacc[g][c * 8 + 1]);
          unsigned int A1 = pk2(sacc[g][c * 8 + 2], sacc[g][c * 8 + 3]);
          unsigned int B0 = pk2(sacc[g][c * 8 + 4], sacc[g][c * 8 + 5]);
          unsigned int B1 = pk2(sacc[g][c * 8 + 6], sacc[g][c * 8 + 7]);
          swap32(A0, B0);
          swap32(A1, B1);
          u32x4 w; w[0] = A0; w[1] = A1; w[2] = B0; w[3] = B1;
          pfrag[g * 2 + c] = __builtin_bit_cast(short8, w);
        }

      // ---- O^T += V^T P^T : lane accumulates its own q's column ----
      const char* Vl = Vsh + cur * 16384;
      #pragma unroll
      for (int dc = 0; dc < 4; ++dc) {
        const int d = dc * 32 + l31;
        #pragma unroll
        for (int kc = 0; kc < 4; ++kc) {
          short8 vf = *(const short8*)(Vl + ((d * 128 + kc * 32 + hi * 16) ^ VSWZ(d)));
          oacc[dc] = __builtin_amdgcn_mfma_f32_32x32x16_bf16(vf, pfrag[kc], oacc[dc], 0, 0, 0);
        }
      }
    }

    // ---- write V(t+1) (paired-kv u32, swizzled) ----
    if (pf) {
      char* Vd = Vsh + (cur ^ 1) * 16384;
      #pragma unroll
      for (int i = 0; i < 4; ++i) {
        int p = vp + i * 8;
        #pragma unroll
        for (int j = 0; j < 4; ++j) {
          int d = vg * 4 + j;
          *(unsigned int*)(Vd + ((d * 128 + p * 4) ^ VSWZ(d))) = pk2(vr0[i][j], vr1[i][j]);
        }
      }
    }
    __syncthreads();
    cur ^= 1;
  }

  // ---- epilogue: O^T -> LDS transpose -> coalesced float4 stores ----
  const float invl = 1.0f / l_run;
  #pragma unroll
  for (int dc = 0; dc < 4; ++dc)
    #pragma unroll
    for (int r = 0; r < 16; ++r) {
      int d = dc * 32 + (r & 3) + 8 * (r >> 2) + 4 * hi;
      Osh[(wv * 32 + l31) * OST + d] = oacc[dc][r] * invl;
    }
  __syncthreads();
  #pragma unroll
  for (int i = 0; i < 16; ++i) {
    int idx = i * 256 + tid;
    int row = idx >> 5, c4 = idx & 31;
    f32x4 v = *(const f32x4*)&Osh[row * OST + c4 * 4];
    *(f32x4*)(Ob + (size_t)(m0 + row) * D_DIM + c4 * 4) = v;
  }
}

extern "C" void kernel_launch(void* const* d_in, const int* in_sizes, int n_in,
                              void* d_out, int out_size, void* d_ws, size_t ws_size,
                              hipStream_t stream) {
  const float* Q = (const float*)d_in[0];
  const float* K = (const float*)d_in[1];
  const float* V = (const float*)d_in[2];
  float* O = (float*)d_out;
  dim3 grid(32 /* B*H */, S_LEN / BM);
  dim3 block(256);
  fa_fwd_kernel<<<grid, block, 0, stream>>>(Q, K, V, O);
}